// Round 10
// baseline (2814.669 us; speedup 1.0000x reference)
//
#include <hip/hip_runtime.h>
#include <hip/hip_bf16.h>
#include <math.h>

#define NN 16384
#define DD 512
#define KSEL 10
#define MCAND 8    // filter keeps top-8 per 2048-col split
#define NSPLIT 8   // column splits for k_sim_topk
#define NPANEL 128 // 16384/128 row panels
#define RESCORE 16 // fp64-rescored candidates per row (top-16 of 64 by filter value)

typedef __bf16 bf16x8 __attribute__((ext_vector_type(8)));
typedef float  f32x4  __attribute__((ext_vector_type(4)));

#define GLOAD_LDS16(gsrc, ldst) \
    __builtin_amdgcn_global_load_lds( \
        (const __attribute__((address_space(1))) void*)(gsrc), \
        (__attribute__((address_space(3))) void*)(ldst), 16, 0, 0)

// ---------------- K1: t = tanh(3 * (emb[idx] @ W^T + b)); also emit bf16 copy ----------------
__global__ __launch_bounds__(256) void k_transform(
    const int* __restrict__ idx, const float* __restrict__ emb,
    const float* __restrict__ W, const float* __restrict__ bias,
    float* __restrict__ t_out, unsigned short* __restrict__ tb_out)
{
    __shared__ float As[32][68];   // [k][m]
    __shared__ float Bs[32][68];   // [k][n]
    const int tid = threadIdx.x;
    const int tx = tid & 15, ty = tid >> 4;
    const int m0 = (blockIdx.x >> 3) << 6;
    const int n0 = (blockIdx.x & 7) << 6;

    float acc[4][4] = {};

    const int f0 = tid, f1 = tid + 256;
    const int r0 = f0 >> 3, c0_ = f0 & 7;
    const int r1 = f1 >> 3, c1_ = f1 & 7;
    const int ga0 = idx[m0 + r0];
    const int ga1 = idx[m0 + r1];

    for (int kc = 0; kc < DD; kc += 32) {
        const float4 a0 = *(const float4*)&emb[(size_t)ga0 * DD + kc + (c0_ << 2)];
        const float4 a1 = *(const float4*)&emb[(size_t)ga1 * DD + kc + (c1_ << 2)];
        const float4 b0 = *(const float4*)&W[(size_t)(n0 + r0) * DD + kc + (c0_ << 2)];
        const float4 b1 = *(const float4*)&W[(size_t)(n0 + r1) * DD + kc + (c1_ << 2)];
        As[(c0_<<2)+0][r0] = a0.x; As[(c0_<<2)+1][r0] = a0.y;
        As[(c0_<<2)+2][r0] = a0.z; As[(c0_<<2)+3][r0] = a0.w;
        As[(c1_<<2)+0][r1] = a1.x; As[(c1_<<2)+1][r1] = a1.y;
        As[(c1_<<2)+2][r1] = a1.z; As[(c1_<<2)+3][r1] = a1.w;
        Bs[(c0_<<2)+0][r0] = b0.x; Bs[(c0_<<2)+1][r0] = b0.y;
        Bs[(c0_<<2)+2][r0] = b0.z; Bs[(c0_<<2)+3][r0] = b0.w;
        Bs[(c1_<<2)+0][r1] = b1.x; Bs[(c1_<<2)+1][r1] = b1.y;
        Bs[(c1_<<2)+2][r1] = b1.z; Bs[(c1_<<2)+3][r1] = b1.w;
        __syncthreads();
        #pragma unroll
        for (int k = 0; k < 32; ++k) {
            const float4 a = *(const float4*)&As[k][ty << 2];
            const float4 b = *(const float4*)&Bs[k][tx << 2];
            const float av[4] = {a.x, a.y, a.z, a.w};
            const float bv[4] = {b.x, b.y, b.z, b.w};
            #pragma unroll
            for (int i = 0; i < 4; ++i)
                #pragma unroll
                for (int j = 0; j < 4; ++j)
                    acc[i][j] = fmaf(av[i], bv[j], acc[i][j]);
        }
        __syncthreads();
    }

    #pragma unroll
    for (int i = 0; i < 4; ++i) {
        const int m = m0 + (ty << 2) + i;
        float o[4];
        union { __hip_bfloat16 h[4]; ushort4 u; } cc;
        #pragma unroll
        for (int j = 0; j < 4; ++j) {
            const int n = n0 + (tx << 2) + j;
            o[j] = tanhf(3.0f * (acc[i][j] + bias[n]));
            cc.h[j] = __float2bfloat16(o[j]);
        }
        *(float4*)&t_out[(size_t)m * DD + n0 + (tx << 2)] =
            make_float4(o[0], o[1], o[2], o[3]);
        *(ushort4*)&tb_out[(size_t)m * DD + n0 + (tx << 2)] = cc.u;
    }
}

// ------------- K2: bf16 MFMA sim filter — A panel resident in LDS, B streamed -------------
// 256 threads (4 waves 2x2, each 64x64). A[128][512] bf16 staged ONCE (128 KB, swizzled);
// per 128-col tile ct: 16 K-steps (BK=32) stream only B (8 KB/step, ring-3, counted
// vmcnt(2) + raw s_barrier, depth-2 prefetch; B panel is XCD-L2-resident via s=bid&7).
// Drain: 8 rounds x 16 cols (cap 16), cv/ci alias B-ring, stride 17.
__global__ __launch_bounds__(256) void k_sim_topk(
    const unsigned short* __restrict__ tb,
    float* __restrict__ pv, unsigned short* __restrict__ pi)
{
    // LDS map (162816 B total):
    //   A @0: 128 rows x 1024 B = 131072
    //   B ring @131072: 3 x 8192 = 24576
    //   topv @155648 [128][8]f32 (4096), topi @159744 [128][8]u16 (2048)
    //   thresh @161792 [128]f32 (512), cnt @162304 [128]i32 (512)
    //   drain alias: cv[128][17]f32 @131072, ci[128][17]i32 @139776 (17408 <= 24576)
    __shared__ __align__(16) char SM[162816];
    float*          topv   = (float*)(SM + 155648);
    unsigned short* topi   = (unsigned short*)(SM + 159744);
    float*          thresh = (float*)(SM + 161792);
    int*            cnt    = (int*)(SM + 162304);
    float*          cv     = (float*)(SM + 131072);
    int*            ci     = (int*)(SM + 139776);

    const int tid  = threadIdx.x;
    const int wave = tid >> 6;     // 0..3
    const int lane = tid & 63;
    const int wr   = wave >> 1;    // 0..1 -> rows wr*64
    const int wc   = wave & 1;     // 0..1 -> cols wc*64

    // XCD decode (perf-only): split s = bid&7 pinned to XCD s -> 2 MB B-panel L2-resident.
    const int bid  = blockIdx.x;
    const int s    = bid & 7;          // 0..7
    const int mblk = bid >> 3;         // 0..127
    const int m0   = mblk << 7;        // 128-row panel
    const int c_begin = s * (NN / NSPLIT);

    if (tid < 128) {
        thresh[tid] = -1e30f;
        cnt[tid] = 0;
        #pragma unroll
        for (int j = 0; j < MCAND; ++j) { topv[tid*MCAND + j] = -1e30f; topi[tid*MCAND + j] = 0xFFFFu; }
    }

    const char* tbb = (const char*)tb;

    // ---- stage A panel once: 1 instruction per row (64 lanes x 16 B = 1024 B) ----
    // LDS linear dest; global source pre-swizzled byte^=( (row&7)<<4 ) (involution).
    for (int i = 0; i < 32; ++i) {
        const int rl = (wave << 5) + i;    // 0..127
        GLOAD_LDS16(tbb + (size_t)(m0 + rl) * 1024 + (size_t)((lane << 4) ^ ((rl & 7) << 4)),
                    SM + (rl << 10));
    }
    asm volatile("s_waitcnt vmcnt(0)" ::: "memory");
    __syncthreads();

    for (int ct = 0; ct < (NN / NSPLIT) / 128; ++ct) {
        const int c0 = c_begin + (ct << 7);
        f32x4 acc[4][4] = {};

        // stage B K-step k into ring[k%3]: 8 KB = 8 instr (2/wave), 16 rows x 64 B each
        auto STAGE_B = [&](int k) {
            char* Bd = SM + 131072 + (k % 3) * 8192;
            const size_t kb = (size_t)k << 6;   // 32 k * 2B
            #pragma unroll
            for (int i_ = 0; i_ < 2; ++i_) {
                const int instr = (wave << 1) + i_;            // 0..7
                const int rl = (instr << 4) + (lane >> 2);     // local B row 0..127
                GLOAD_LDS16(tbb + (size_t)(c0 + rl) * 1024 + kb
                                + (size_t)((((lane & 3) << 4)) ^ ((rl & 3) << 4)),
                            Bd + (instr << 10));
            }
        };

        auto COMPUTE = [&](int kc) {
            const char* Bc = SM + 131072 + (kc % 3) * 8192;
            const int u = lane >> 4;
            bf16x8 af[4], bf[4];
            #pragma unroll
            for (int m = 0; m < 4; ++m) {
                const int row = (wr << 6) + (m << 4) + (lane & 15);
                af[m] = *(const bf16x8*)(SM + (row << 10)
                        + (((kc << 6) + (u << 4)) ^ ((row & 7) << 4)));
            }
            #pragma unroll
            for (int n = 0; n < 4; ++n) {
                const int row = (wc << 6) + (n << 4) + (lane & 15);
                bf[n] = *(const bf16x8*)(Bc + (row << 6) + ((u ^ (row & 3)) << 4));
            }
            #pragma unroll
            for (int m = 0; m < 4; ++m)
                #pragma unroll
                for (int n = 0; n < 4; ++n)
                    acc[m][n] = __builtin_amdgcn_mfma_f32_16x16x32_bf16(
                        af[m], bf[n], acc[m][n], 0, 0, 0);
        };

        // prologue: B steps 0,1 in flight (2 loads each per wave)
        STAGE_B(0); STAGE_B(1);
        for (int kc = 0; kc < 14; ++kc) {
            asm volatile("s_waitcnt vmcnt(2)" ::: "memory");  // own STAGE_B(kc) landed
            __builtin_amdgcn_s_barrier();                      // all waves' STAGE_B(kc) landed
            STAGE_B(kc + 2);                                   // ring[(kc+2)%3] disjoint from COMPUTE(kc)
            COMPUTE(kc);
        }
        asm volatile("s_waitcnt vmcnt(2)" ::: "memory");
        __builtin_amdgcn_s_barrier();
        COMPUTE(14);
        asm volatile("s_waitcnt vmcnt(0)" ::: "memory");
        __builtin_amdgcn_s_barrier();
        COMPUTE(15);

        __syncthreads();   // all ring reads done before cv/ci alias-writes

        // ---- drain: 8 rounds of 16 cols; cap 16 == round width; stride-17 ----
        #pragma unroll
        for (int rnd = 0; rnd < 8; ++rnd) {
            const int wcr = rnd >> 2;
            const int nf = rnd & 3;
            if (wc == wcr) {
                #pragma unroll
                for (int m = 0; m < 4; ++m) {
                    #pragma unroll
                    for (int j = 0; j < 4; ++j) {
                        const int row = (wr << 6) + (m << 4) + ((lane >> 4) << 2) + j;
                        const float v = acc[m][nf][j];
                        if (v >= thresh[row]) {
                            const int p = atomicAdd(&cnt[row], 1);
                            cv[row * 17 + p] = v;
                            ci[row * 17 + p] = c0 + (wcr << 6) + (nf << 4) + (lane & 15);
                        }
                    }
                }
            }
            __syncthreads();
            if (tid < 128) {
                const int r = tid;
                const int n_ = cnt[r];
                float* tv = &topv[r * MCAND];
                unsigned short* ti = &topi[r * MCAND];
                for (int q = 0; q < n_; ++q) {
                    const float v = cv[r * 17 + q];
                    const unsigned short c = (unsigned short)ci[r * 17 + q];
                    if (v > tv[MCAND-1] || (v == tv[MCAND-1] && c < ti[MCAND-1])) {
                        int p = MCAND - 1;
                        while (p > 0 && (v > tv[p-1] || (v == tv[p-1] && c < ti[p-1]))) {
                            tv[p] = tv[p-1]; ti[p] = ti[p-1]; --p;
                        }
                        tv[p] = v; ti[p] = c;
                    }
                }
                cnt[r] = 0;
                thresh[r] = tv[MCAND-1];
            }
            __syncthreads();
        }
    }

    if (tid < 128) {
        const size_t base = (((size_t)s * NPANEL + mblk) * 128 + tid) * MCAND;
        #pragma unroll
        for (int j = 0; j < MCAND; ++j) {
            pv[base + j] = topv[tid * MCAND + j];
            pi[base + j] = topi[tid * MCAND + j];
        }
    }
}

// ------------- K3: wave bitonic top-16-of-64 by filter value, fp64 rescore, scatter -------------
__global__ __launch_bounds__(256) void k_rescore(
    const float* __restrict__ t, const float* __restrict__ pv,
    const unsigned short* __restrict__ pi, float* __restrict__ out)
{
    const int wave = threadIdx.x >> 6;
    const int lane = threadIdx.x & 63;
    const int r = blockIdx.x * 4 + wave;
    const int panel = r >> 7, local = r & 127;

    // lane q holds candidate (split q>>3, slot q&7)
    const int sp = lane >> 3, slot = lane & 7;
    const size_t cbase = (((size_t)sp * NPANEL + panel) * 128 + local) * MCAND;
    const float v = pv[cbase + slot];
    const unsigned int idxc = pi[cbase + slot];
    // monotone key: v desc, idx asc. empty slots (v=-1e30, idx=0xFFFF) sort last.
    const unsigned int u = __float_as_uint(v);
    const unsigned int mkey = (u & 0x80000000u) ? ~u : (u | 0x80000000u);
    unsigned long long key = ((unsigned long long)mkey << 16) |
                             (unsigned long long)((~idxc) & 0xFFFFu);

    // 64-lane bitonic sort, descending
    #pragma unroll
    for (int k = 2; k <= 64; k <<= 1) {
        #pragma unroll
        for (int j = k >> 1; j > 0; j >>= 1) {
            const unsigned long long other = __shfl_xor(key, j, 64);
            const bool lower = (lane & j) == 0;
            const bool ascBlock = (lane & k) == 0;
            const bool takeMax = (lower == ascBlock);
            const bool mineBigger = key > other;
            key = (takeMax == mineBigger) ? key : other;
        }
    }
    const int cid = (int)((~(unsigned int)key) & 0xFFFFu);  // lanes 0..15: top-16 cand columns

    const float4 a0 = *(const float4*)&t[(size_t)r * DD + lane * 8];
    const float4 a1 = *(const float4*)&t[(size_t)r * DD + lane * 8 + 4];

    double bestv[KSEL];
    int    besti[KSEL];
    #pragma unroll
    for (int j = 0; j < KSEL; ++j) { bestv[j] = -1e300; besti[j] = 0x7fffffff; }

    for (int q = 0; q < RESCORE; ++q) {
        const int c = __shfl(cid, q, 64);
        const float4 v0 = *(const float4*)&t[(size_t)c * DD + lane * 8];
        const float4 v1 = *(const float4*)&t[(size_t)c * DD + lane * 8 + 4];
        double sdot = 0.0;
        sdot += (double)a0.x * (double)v0.x;
        sdot += (double)a0.y * (double)v0.y;
        sdot += (double)a0.z * (double)v0.z;
        sdot += (double)a0.w * (double)v0.w;
        sdot += (double)a1.x * (double)v1.x;
        sdot += (double)a1.y * (double)v1.y;
        sdot += (double)a1.z * (double)v1.z;
        sdot += (double)a1.w * (double)v1.w;
        #pragma unroll
        for (int off = 32; off > 0; off >>= 1)
            sdot += __shfl_down(sdot, off, 64);
        if (lane == 0) {
            if (sdot > bestv[KSEL-1] || (sdot == bestv[KSEL-1] && c < besti[KSEL-1])) {
                int p = KSEL - 1;
                while (p > 0 && (sdot > bestv[p-1] ||
                                 (sdot == bestv[p-1] && c < besti[p-1]))) {
                    bestv[p] = bestv[p-1]; besti[p] = besti[p-1]; --p;
                }
                bestv[p] = sdot; besti[p] = c;
            }
        }
    }

    if (lane == 0) {
        #pragma unroll
        for (int j = 0; j < KSEL; ++j)
            out[(size_t)besti[j] * NN + r] = 1.0f;
    }
}

extern "C" void kernel_launch(void* const* d_in, const int* in_sizes, int n_in,
                              void* d_out, int out_size, void* d_ws, size_t ws_size,
                              hipStream_t stream) {
    const int*   idx  = (const int*)d_in[0];
    const float* emb  = (const float*)d_in[1];
    const float* linw = (const float*)d_in[2];
    const float* linb = (const float*)d_in[3];
    float* out = (float*)d_out;

    // ws: t f32 32MB @0; tb bf16 16MB @32M; pv f32 4MB @48M; pi u16 2MB @52M
    float*          t  = (float*)d_ws;
    unsigned short* tb = (unsigned short*)((char*)d_ws + (size_t)32 * 1024 * 1024);
    float*          pv = (float*)((char*)d_ws + (size_t)48 * 1024 * 1024);
    unsigned short* pi = (unsigned short*)((char*)d_ws + (size_t)52 * 1024 * 1024);

    (void)hipMemsetAsync(d_out, 0, (size_t)NN * (size_t)NN * sizeof(float), stream);

    k_transform<<<dim3(256 * 8), dim3(256), 0, stream>>>(idx, emb, linw, linb, t, tb);
    k_sim_topk<<<dim3(NPANEL * NSPLIT), dim3(256), 0, stream>>>(tb, pv, pi);
    k_rescore<<<dim3(NN / 4), dim3(256), 0, stream>>>(t, pv, pi, out);
}

// Round 11
// 2150.239 us; speedup vs baseline: 1.3090x; 1.3090x over previous
//
#include <hip/hip_runtime.h>
#include <hip/hip_bf16.h>
#include <math.h>

#define NN 16384
#define DD 512
#define KSEL 10
#define MCAND 8    // filter keeps top-8 per 2048-col split
#define NSPLIT 8   // column splits for k_sim_topk
#define NPANEL 128 // 16384/128 row panels
#define RESCORE 16 // fp64-rescored candidates per row (top-16 of 64 by filter value)

typedef __bf16 bf16x8 __attribute__((ext_vector_type(8)));
typedef float  f32x4  __attribute__((ext_vector_type(4)));

#define GLOAD_LDS16(gsrc, ldst) \
    __builtin_amdgcn_global_load_lds( \
        (const __attribute__((address_space(1))) void*)(gsrc), \
        (__attribute__((address_space(3))) void*)(ldst), 16, 0, 0)

// ---------------- K1: t = tanh(3 * (emb[idx] @ W^T + b)); also emit bf16 copy ----------------
__global__ __launch_bounds__(256) void k_transform(
    const int* __restrict__ idx, const float* __restrict__ emb,
    const float* __restrict__ W, const float* __restrict__ bias,
    float* __restrict__ t_out, unsigned short* __restrict__ tb_out)
{
    __shared__ float As[32][68];   // [k][m]
    __shared__ float Bs[32][68];   // [k][n]
    const int tid = threadIdx.x;
    const int tx = tid & 15, ty = tid >> 4;
    const int m0 = (blockIdx.x >> 3) << 6;
    const int n0 = (blockIdx.x & 7) << 6;

    float acc[4][4] = {};

    const int f0 = tid, f1 = tid + 256;
    const int r0 = f0 >> 3, c0_ = f0 & 7;
    const int r1 = f1 >> 3, c1_ = f1 & 7;
    const int ga0 = idx[m0 + r0];
    const int ga1 = idx[m0 + r1];

    for (int kc = 0; kc < DD; kc += 32) {
        const float4 a0 = *(const float4*)&emb[(size_t)ga0 * DD + kc + (c0_ << 2)];
        const float4 a1 = *(const float4*)&emb[(size_t)ga1 * DD + kc + (c1_ << 2)];
        const float4 b0 = *(const float4*)&W[(size_t)(n0 + r0) * DD + kc + (c0_ << 2)];
        const float4 b1 = *(const float4*)&W[(size_t)(n0 + r1) * DD + kc + (c1_ << 2)];
        As[(c0_<<2)+0][r0] = a0.x; As[(c0_<<2)+1][r0] = a0.y;
        As[(c0_<<2)+2][r0] = a0.z; As[(c0_<<2)+3][r0] = a0.w;
        As[(c1_<<2)+0][r1] = a1.x; As[(c1_<<2)+1][r1] = a1.y;
        As[(c1_<<2)+2][r1] = a1.z; As[(c1_<<2)+3][r1] = a1.w;
        Bs[(c0_<<2)+0][r0] = b0.x; Bs[(c0_<<2)+1][r0] = b0.y;
        Bs[(c0_<<2)+2][r0] = b0.z; Bs[(c0_<<2)+3][r0] = b0.w;
        Bs[(c1_<<2)+0][r1] = b1.x; Bs[(c1_<<2)+1][r1] = b1.y;
        Bs[(c1_<<2)+2][r1] = b1.z; Bs[(c1_<<2)+3][r1] = b1.w;
        __syncthreads();
        #pragma unroll
        for (int k = 0; k < 32; ++k) {
            const float4 a = *(const float4*)&As[k][ty << 2];
            const float4 b = *(const float4*)&Bs[k][tx << 2];
            const float av[4] = {a.x, a.y, a.z, a.w};
            const float bv[4] = {b.x, b.y, b.z, b.w};
            #pragma unroll
            for (int i = 0; i < 4; ++i)
                #pragma unroll
                for (int j = 0; j < 4; ++j)
                    acc[i][j] = fmaf(av[i], bv[j], acc[i][j]);
        }
        __syncthreads();
    }

    #pragma unroll
    for (int i = 0; i < 4; ++i) {
        const int m = m0 + (ty << 2) + i;
        float o[4];
        union { __hip_bfloat16 h[4]; ushort4 u; } cc;
        #pragma unroll
        for (int j = 0; j < 4; ++j) {
            const int n = n0 + (tx << 2) + j;
            o[j] = tanhf(3.0f * (acc[i][j] + bias[n]));
            cc.h[j] = __float2bfloat16(o[j]);
        }
        *(float4*)&t_out[(size_t)m * DD + n0 + (tx << 2)] =
            make_float4(o[0], o[1], o[2], o[3]);
        *(ushort4*)&tb_out[(size_t)m * DD + n0 + (tx << 2)] = cc.u;
    }
}

// ------------- K2: bf16 MFMA sim filter — m97-style, 39.9 KB LDS, 4 blocks/CU -------------
// 128x128 tile, 4 waves (2x2, each 64x64 via 4x4 frags of 16x16x32 bf16), BK=64,
// single-buffered, plain __syncthreads (multi-block residency hides the vmcnt(0) drain
// — m114 implicit overlap; no hand pipelining). LDS: A 16K @0, B 16K @16384,
// top-8 aux @32768..39935. Drain: 8 rounds x 16 cols (cap 16), cv/ci stride-17
// ALIAS the A/B buffers (re-staged next ct).
__global__ __launch_bounds__(256, 4) void k_sim_topk(
    const unsigned short* __restrict__ tb,
    float* __restrict__ pv, unsigned short* __restrict__ pi)
{
    // LDS map (39936 B -> 4 blocks/CU):
    //   Abuf @0 (16384), Bbuf @16384 (16384)
    //   topv @32768 [128][8]f32 (4096), topi @36864 [128][8]u16 (2048)
    //   thresh @38912 [128]f32 (512), cnt @39424 [128]i32 (512)
    //   drain alias: cv[128][17]f32 @0 (8704), ci[128][17]i32 @8704 (8704) -> 17408 <= 32768
    __shared__ __align__(16) char SM[39936];
    float*          topv   = (float*)(SM + 32768);
    unsigned short* topi   = (unsigned short*)(SM + 36864);
    float*          thresh = (float*)(SM + 38912);
    int*            cnt    = (int*)(SM + 39424);
    float*          cv     = (float*)(SM);
    int*            ci     = (int*)(SM + 8704);

    const int tid  = threadIdx.x;
    const int wave = tid >> 6;     // 0..3
    const int lane = tid & 63;
    const int wr   = wave >> 1;    // 0..1 -> rows wr*64
    const int wc   = wave & 1;     // 0..1 -> cols wc*64

    // XCD decode (perf-only): split s = bid&7 pinned to XCD s -> 2 MB B-panel L2-resident.
    const int bid  = blockIdx.x;
    const int s    = bid & 7;          // 0..7
    const int mblk = bid >> 3;         // 0..127
    const int m0   = mblk << 7;        // 128-row panel
    const int c_begin = s * (NN / NSPLIT);

    if (tid < 128) {
        thresh[tid] = -1e30f;
        cnt[tid] = 0;
        #pragma unroll
        for (int j = 0; j < MCAND; ++j) { topv[tid*MCAND + j] = -1e30f; topi[tid*MCAND + j] = 0xFFFFu; }
    }
    __syncthreads();

    const char* tbb = (const char*)tb;
    const int lr8 = lane >> 3;                 // row within 8-row staging group
    const int scx = ((lane & 7) ^ lr8) << 4;   // pre-swizzled byte offset (involution)

    for (int ct = 0; ct < (NN / NSPLIT) / 128; ++ct) {
        const int c0 = c_begin + (ct << 7);
        f32x4 acc[4][4] = {};

        for (int kc8 = 0; kc8 < 8; ++kc8) {
            const size_t kb = (size_t)kc8 << 7;   // 64 k * 2B
            // stage A and B tiles (4+4 gload_lds per wave, 1 KB each)
            #pragma unroll
            for (int i_ = 0; i_ < 4; ++i_) {
                const int ai = (wave << 2) + i_;   // 0..15, covers rows ai*8..ai*8+7
                GLOAD_LDS16(tbb + (size_t)(m0 + (ai << 3) + lr8) * 1024 + kb + scx,
                            SM + (ai << 10));
                GLOAD_LDS16(tbb + (size_t)(c0 + (ai << 3) + lr8) * 1024 + kb + scx,
                            SM + 16384 + (ai << 10));
            }
            __syncthreads();   // vmcnt(0)+barrier: tiles visible (multi-block hides the drain)

            #pragma unroll
            for (int ks = 0; ks < 2; ++ks) {
                bf16x8 af[4], bf[4];
                #pragma unroll
                for (int m = 0; m < 4; ++m) {
                    const int row = (wr << 6) + (m << 4) + (lane & 15);
                    const int corig = (ks << 2) + (lane >> 4);
                    af[m] = *(const bf16x8*)(SM + (row << 7) + ((corig ^ (row & 7)) << 4));
                }
                #pragma unroll
                for (int n = 0; n < 4; ++n) {
                    const int row = (wc << 6) + (n << 4) + (lane & 15);
                    const int corig = (ks << 2) + (lane >> 4);
                    bf[n] = *(const bf16x8*)(SM + 16384 + (row << 7) + ((corig ^ (row & 7)) << 4));
                }
                #pragma unroll
                for (int m = 0; m < 4; ++m)
                    #pragma unroll
                    for (int n = 0; n < 4; ++n)
                        acc[m][n] = __builtin_amdgcn_mfma_f32_16x16x32_bf16(
                            af[m], bf[n], acc[m][n], 0, 0, 0);
            }
            __syncthreads();   // all reads done before next stage overwrites
        }

        // ---- drain: 8 rounds of 16 cols; cap 16 == round width; stride-17; alias A/B ----
        #pragma unroll
        for (int rnd = 0; rnd < 8; ++rnd) {
            const int wcr = rnd >> 2;
            const int nf = rnd & 3;
            if (wc == wcr) {
                #pragma unroll
                for (int m = 0; m < 4; ++m) {
                    #pragma unroll
                    for (int j = 0; j < 4; ++j) {
                        const int row = (wr << 6) + (m << 4) + ((lane >> 4) << 2) + j;
                        const float v = acc[m][nf][j];
                        if (v >= thresh[row]) {
                            const int p = atomicAdd(&cnt[row], 1);
                            cv[row * 17 + p] = v;
                            ci[row * 17 + p] = c0 + (wcr << 6) + (nf << 4) + (lane & 15);
                        }
                    }
                }
            }
            __syncthreads();
            if (tid < 128) {
                const int r = tid;
                const int n_ = cnt[r];
                float* tv = &topv[r * MCAND];
                unsigned short* ti = &topi[r * MCAND];
                for (int q = 0; q < n_; ++q) {
                    const float v = cv[r * 17 + q];
                    const unsigned short c = (unsigned short)ci[r * 17 + q];
                    if (v > tv[MCAND-1] || (v == tv[MCAND-1] && c < ti[MCAND-1])) {
                        int p = MCAND - 1;
                        while (p > 0 && (v > tv[p-1] || (v == tv[p-1] && c < ti[p-1]))) {
                            tv[p] = tv[p-1]; ti[p] = ti[p-1]; --p;
                        }
                        tv[p] = v; ti[p] = c;
                    }
                }
                cnt[r] = 0;
                thresh[r] = tv[MCAND-1];
            }
            __syncthreads();
        }
    }

    if (tid < 128) {
        const size_t base = (((size_t)s * NPANEL + mblk) * 128 + tid) * MCAND;
        #pragma unroll
        for (int j = 0; j < MCAND; ++j) {
            pv[base + j] = topv[tid * MCAND + j];
            pi[base + j] = topi[tid * MCAND + j];
        }
    }
}

// ------------- K3: wave bitonic top-16-of-64 by filter value, fp64 rescore, scatter -------------
__global__ __launch_bounds__(256) void k_rescore(
    const float* __restrict__ t, const float* __restrict__ pv,
    const unsigned short* __restrict__ pi, float* __restrict__ out)
{
    const int wave = threadIdx.x >> 6;
    const int lane = threadIdx.x & 63;
    const int r = blockIdx.x * 4 + wave;
    const int panel = r >> 7, local = r & 127;

    // lane q holds candidate (split q>>3, slot q&7)
    const int sp = lane >> 3, slot = lane & 7;
    const size_t cbase = (((size_t)sp * NPANEL + panel) * 128 + local) * MCAND;
    const float v = pv[cbase + slot];
    const unsigned int idxc = pi[cbase + slot];
    // monotone key: v desc, idx asc. empty slots (v=-1e30, idx=0xFFFF) sort last.
    const unsigned int u = __float_as_uint(v);
    const unsigned int mkey = (u & 0x80000000u) ? ~u : (u | 0x80000000u);
    unsigned long long key = ((unsigned long long)mkey << 16) |
                             (unsigned long long)((~idxc) & 0xFFFFu);

    // 64-lane bitonic sort, descending
    #pragma unroll
    for (int k = 2; k <= 64; k <<= 1) {
        #pragma unroll
        for (int j = k >> 1; j > 0; j >>= 1) {
            const unsigned long long other = __shfl_xor(key, j, 64);
            const bool lower = (lane & j) == 0;
            const bool ascBlock = (lane & k) == 0;
            const bool takeMax = (lower == ascBlock);
            const bool mineBigger = key > other;
            key = (takeMax == mineBigger) ? key : other;
        }
    }
    const int cid = (int)((~(unsigned int)key) & 0xFFFFu);  // lanes 0..15: top-16 cand columns

    const float4 a0 = *(const float4*)&t[(size_t)r * DD + lane * 8];
    const float4 a1 = *(const float4*)&t[(size_t)r * DD + lane * 8 + 4];

    double bestv[KSEL];
    int    besti[KSEL];
    #pragma unroll
    for (int j = 0; j < KSEL; ++j) { bestv[j] = -1e300; besti[j] = 0x7fffffff; }

    for (int q = 0; q < RESCORE; ++q) {
        const int c = __shfl(cid, q, 64);
        const float4 v0 = *(const float4*)&t[(size_t)c * DD + lane * 8];
        const float4 v1 = *(const float4*)&t[(size_t)c * DD + lane * 8 + 4];
        double sdot = 0.0;
        sdot += (double)a0.x * (double)v0.x;
        sdot += (double)a0.y * (double)v0.y;
        sdot += (double)a0.z * (double)v0.z;
        sdot += (double)a0.w * (double)v0.w;
        sdot += (double)a1.x * (double)v1.x;
        sdot += (double)a1.y * (double)v1.y;
        sdot += (double)a1.z * (double)v1.z;
        sdot += (double)a1.w * (double)v1.w;
        #pragma unroll
        for (int off = 32; off > 0; off >>= 1)
            sdot += __shfl_down(sdot, off, 64);
        if (lane == 0) {
            if (sdot > bestv[KSEL-1] || (sdot == bestv[KSEL-1] && c < besti[KSEL-1])) {
                int p = KSEL - 1;
                while (p > 0 && (sdot > bestv[p-1] ||
                                 (sdot == bestv[p-1] && c < besti[p-1]))) {
                    bestv[p] = bestv[p-1]; besti[p] = besti[p-1]; --p;
                }
                bestv[p] = sdot; besti[p] = c;
            }
        }
    }

    if (lane == 0) {
        #pragma unroll
        for (int j = 0; j < KSEL; ++j)
            out[(size_t)besti[j] * NN + r] = 1.0f;
    }
}

extern "C" void kernel_launch(void* const* d_in, const int* in_sizes, int n_in,
                              void* d_out, int out_size, void* d_ws, size_t ws_size,
                              hipStream_t stream) {
    const int*   idx  = (const int*)d_in[0];
    const float* emb  = (const float*)d_in[1];
    const float* linw = (const float*)d_in[2];
    const float* linb = (const float*)d_in[3];
    float* out = (float*)d_out;

    // ws: t f32 32MB @0; tb bf16 16MB @32M; pv f32 4MB @48M; pi u16 2MB @52M
    float*          t  = (float*)d_ws;
    unsigned short* tb = (unsigned short*)((char*)d_ws + (size_t)32 * 1024 * 1024);
    float*          pv = (float*)((char*)d_ws + (size_t)48 * 1024 * 1024);
    unsigned short* pi = (unsigned short*)((char*)d_ws + (size_t)52 * 1024 * 1024);

    (void)hipMemsetAsync(d_out, 0, (size_t)NN * (size_t)NN * sizeof(float), stream);

    k_transform<<<dim3(256 * 8), dim3(256), 0, stream>>>(idx, emb, linw, linb, t, tb);
    k_sim_topk<<<dim3(NPANEL * NSPLIT), dim3(256), 0, stream>>>(tb, pv, pi);
    k_rescore<<<dim3(NN / 4), dim3(256), 0, stream>>>(t, pv, pi, out);
}

// Round 12
// 2130.192 us; speedup vs baseline: 1.3213x; 1.0094x over previous
//
#include <hip/hip_runtime.h>
#include <hip/hip_bf16.h>
#include <math.h>

#define NN 16384
#define DD 512
#define KSEL 10
#define MCAND 8    // filter keeps top-8 per 2048-col split
#define NSPLIT 8   // column splits for k_sim_topk
#define NPANEL 128 // 16384/128 row panels
#define RESCORE 16 // fp64-rescored candidates per row (top-16 of 64 by filter value)

typedef __bf16 bf16x8 __attribute__((ext_vector_type(8)));
typedef float  f32x4  __attribute__((ext_vector_type(4)));

#define GLOAD_LDS16(gsrc, ldst) \
    __builtin_amdgcn_global_load_lds( \
        (const __attribute__((address_space(1))) void*)(gsrc), \
        (__attribute__((address_space(3))) void*)(ldst), 16, 0, 0)

// ---------------- K1: t = tanh(3 * (emb[idx] @ W^T + b)); also emit bf16 copy ----------------
__global__ __launch_bounds__(256) void k_transform(
    const int* __restrict__ idx, const float* __restrict__ emb,
    const float* __restrict__ W, const float* __restrict__ bias,
    float* __restrict__ t_out, unsigned short* __restrict__ tb_out)
{
    __shared__ float As[32][68];   // [k][m]
    __shared__ float Bs[32][68];   // [k][n]
    const int tid = threadIdx.x;
    const int tx = tid & 15, ty = tid >> 4;
    const int m0 = (blockIdx.x >> 3) << 6;
    const int n0 = (blockIdx.x & 7) << 6;

    float acc[4][4] = {};

    const int f0 = tid, f1 = tid + 256;
    const int r0 = f0 >> 3, c0_ = f0 & 7;
    const int r1 = f1 >> 3, c1_ = f1 & 7;
    const int ga0 = idx[m0 + r0];
    const int ga1 = idx[m0 + r1];

    for (int kc = 0; kc < DD; kc += 32) {
        const float4 a0 = *(const float4*)&emb[(size_t)ga0 * DD + kc + (c0_ << 2)];
        const float4 a1 = *(const float4*)&emb[(size_t)ga1 * DD + kc + (c1_ << 2)];
        const float4 b0 = *(const float4*)&W[(size_t)(n0 + r0) * DD + kc + (c0_ << 2)];
        const float4 b1 = *(const float4*)&W[(size_t)(n0 + r1) * DD + kc + (c1_ << 2)];
        As[(c0_<<2)+0][r0] = a0.x; As[(c0_<<2)+1][r0] = a0.y;
        As[(c0_<<2)+2][r0] = a0.z; As[(c0_<<2)+3][r0] = a0.w;
        As[(c1_<<2)+0][r1] = a1.x; As[(c1_<<2)+1][r1] = a1.y;
        As[(c1_<<2)+2][r1] = a1.z; As[(c1_<<2)+3][r1] = a1.w;
        Bs[(c0_<<2)+0][r0] = b0.x; Bs[(c0_<<2)+1][r0] = b0.y;
        Bs[(c0_<<2)+2][r0] = b0.z; Bs[(c0_<<2)+3][r0] = b0.w;
        Bs[(c1_<<2)+0][r1] = b1.x; Bs[(c1_<<2)+1][r1] = b1.y;
        Bs[(c1_<<2)+2][r1] = b1.z; Bs[(c1_<<2)+3][r1] = b1.w;
        __syncthreads();
        #pragma unroll
        for (int k = 0; k < 32; ++k) {
            const float4 a = *(const float4*)&As[k][ty << 2];
            const float4 b = *(const float4*)&Bs[k][tx << 2];
            const float av[4] = {a.x, a.y, a.z, a.w};
            const float bv[4] = {b.x, b.y, b.z, b.w};
            #pragma unroll
            for (int i = 0; i < 4; ++i)
                #pragma unroll
                for (int j = 0; j < 4; ++j)
                    acc[i][j] = fmaf(av[i], bv[j], acc[i][j]);
        }
        __syncthreads();
    }

    #pragma unroll
    for (int i = 0; i < 4; ++i) {
        const int m = m0 + (ty << 2) + i;
        float o[4];
        union { __hip_bfloat16 h[4]; ushort4 u; } cc;
        #pragma unroll
        for (int j = 0; j < 4; ++j) {
            const int n = n0 + (tx << 2) + j;
            o[j] = tanhf(3.0f * (acc[i][j] + bias[n]));
            cc.h[j] = __float2bfloat16(o[j]);
        }
        *(float4*)&t_out[(size_t)m * DD + n0 + (tx << 2)] =
            make_float4(o[0], o[1], o[2], o[3]);
        *(ushort4*)&tb_out[(size_t)m * DD + n0 + (tx << 2)] = cc.u;
    }
}

// ------------- K2: bf16 MFMA sim filter — R11 structure + L2-locality block remap -------------
// 128x128 tile, 4 waves (2x2), BK=64, single-buffered, plain __syncthreads,
// 39.9 KB LDS -> 4 blocks/CU. NEW: XCD hosts 16 panels x all 8 splits
// (panel = (bid&7)*16 + ((bid>>3)&15), split = bid>>7): per-XCD A working set
// 2 MB (L2-resident across the 16x ct-reuse) + lockstep B tiles ~1 MB.
__global__ __launch_bounds__(256, 4) void k_sim_topk(
    const unsigned short* __restrict__ tb,
    float* __restrict__ pv, unsigned short* __restrict__ pi)
{
    // LDS map (39936 B -> 4 blocks/CU):
    //   Abuf @0 (16384), Bbuf @16384 (16384)
    //   topv @32768 [128][8]f32 (4096), topi @36864 [128][8]u16 (2048)
    //   thresh @38912 [128]f32 (512), cnt @39424 [128]i32 (512)
    //   drain alias: cv[128][17]f32 @0, ci[128][17]i32 @8704
    __shared__ __align__(16) char SM[39936];
    float*          topv   = (float*)(SM + 32768);
    unsigned short* topi   = (unsigned short*)(SM + 36864);
    float*          thresh = (float*)(SM + 38912);
    int*            cnt    = (int*)(SM + 39424);
    float*          cv     = (float*)(SM);
    int*            ci     = (int*)(SM + 8704);

    const int tid  = threadIdx.x;
    const int wave = tid >> 6;     // 0..3
    const int lane = tid & 63;
    const int wr   = wave >> 1;    // 0..1 -> rows wr*64
    const int wc   = wave & 1;     // 0..1 -> cols wc*64

    // L2-locality decode (perf-only; assumes bid->XCD round-robin bid&7):
    // XCD x hosts panels 16x..16x+15 for ALL splits -> A ws 2 MB L2-resident,
    // B tiles read in lockstep by the 16 same-split blocks (~1 MB instantaneous).
    const int bid  = blockIdx.x;
    const int xcd  = bid & 7;
    const int pg   = bid >> 3;                  // 0..127
    const int mblk = (xcd << 4) | (pg & 15);    // 0..127, bijective
    const int s    = pg >> 4;                   // 0..7
    const int m0   = mblk << 7;                 // 128-row panel
    const int c_begin = s * (NN / NSPLIT);

    if (tid < 128) {
        thresh[tid] = -1e30f;
        cnt[tid] = 0;
        #pragma unroll
        for (int j = 0; j < MCAND; ++j) { topv[tid*MCAND + j] = -1e30f; topi[tid*MCAND + j] = 0xFFFFu; }
    }
    __syncthreads();

    const char* tbb = (const char*)tb;
    const int lr8 = lane >> 3;                 // row within 8-row staging group
    const int scx = ((lane & 7) ^ lr8) << 4;   // pre-swizzled byte offset (involution)

    for (int ct = 0; ct < (NN / NSPLIT) / 128; ++ct) {
        const int c0 = c_begin + (ct << 7);
        f32x4 acc[4][4] = {};

        for (int kc8 = 0; kc8 < 8; ++kc8) {
            const size_t kb = (size_t)kc8 << 7;   // 64 k * 2B
            // stage A and B tiles (4+4 gload_lds per wave, 1 KB each)
            #pragma unroll
            for (int i_ = 0; i_ < 4; ++i_) {
                const int ai = (wave << 2) + i_;   // 0..15, covers rows ai*8..ai*8+7
                GLOAD_LDS16(tbb + (size_t)(m0 + (ai << 3) + lr8) * 1024 + kb + scx,
                            SM + (ai << 10));
                GLOAD_LDS16(tbb + (size_t)(c0 + (ai << 3) + lr8) * 1024 + kb + scx,
                            SM + 16384 + (ai << 10));
            }
            __syncthreads();   // vmcnt(0)+barrier: tiles visible (multi-block hides the drain)

            #pragma unroll
            for (int ks = 0; ks < 2; ++ks) {
                bf16x8 af[4], bf[4];
                #pragma unroll
                for (int m = 0; m < 4; ++m) {
                    const int row = (wr << 6) + (m << 4) + (lane & 15);
                    const int corig = (ks << 2) + (lane >> 4);
                    af[m] = *(const bf16x8*)(SM + (row << 7) + ((corig ^ (row & 7)) << 4));
                }
                #pragma unroll
                for (int n = 0; n < 4; ++n) {
                    const int row = (wc << 6) + (n << 4) + (lane & 15);
                    const int corig = (ks << 2) + (lane >> 4);
                    bf[n] = *(const bf16x8*)(SM + 16384 + (row << 7) + ((corig ^ (row & 7)) << 4));
                }
                #pragma unroll
                for (int m = 0; m < 4; ++m)
                    #pragma unroll
                    for (int n = 0; n < 4; ++n)
                        acc[m][n] = __builtin_amdgcn_mfma_f32_16x16x32_bf16(
                            af[m], bf[n], acc[m][n], 0, 0, 0);
            }
            __syncthreads();   // all reads done before next stage overwrites
        }

        // ---- drain: 8 rounds of 16 cols; cap 16 == round width; stride-17; alias A/B ----
        #pragma unroll
        for (int rnd = 0; rnd < 8; ++rnd) {
            const int wcr = rnd >> 2;
            const int nf = rnd & 3;
            if (wc == wcr) {
                #pragma unroll
                for (int m = 0; m < 4; ++m) {
                    #pragma unroll
                    for (int j = 0; j < 4; ++j) {
                        const int row = (wr << 6) + (m << 4) + ((lane >> 4) << 2) + j;
                        const float v = acc[m][nf][j];
                        if (v >= thresh[row]) {
                            const int p = atomicAdd(&cnt[row], 1);
                            cv[row * 17 + p] = v;
                            ci[row * 17 + p] = c0 + (wcr << 6) + (nf << 4) + (lane & 15);
                        }
                    }
                }
            }
            __syncthreads();
            if (tid < 128) {
                const int r = tid;
                const int n_ = cnt[r];
                float* tv = &topv[r * MCAND];
                unsigned short* ti = &topi[r * MCAND];
                for (int q = 0; q < n_; ++q) {
                    const float v = cv[r * 17 + q];
                    const unsigned short c = (unsigned short)ci[r * 17 + q];
                    if (v > tv[MCAND-1] || (v == tv[MCAND-1] && c < ti[MCAND-1])) {
                        int p = MCAND - 1;
                        while (p > 0 && (v > tv[p-1] || (v == tv[p-1] && c < ti[p-1]))) {
                            tv[p] = tv[p-1]; ti[p] = ti[p-1]; --p;
                        }
                        tv[p] = v; ti[p] = c;
                    }
                }
                cnt[r] = 0;
                thresh[r] = tv[MCAND-1];
            }
            __syncthreads();
        }
    }

    if (tid < 128) {
        const size_t base = (((size_t)s * NPANEL + mblk) * 128 + tid) * MCAND;
        #pragma unroll
        for (int j = 0; j < MCAND; ++j) {
            pv[base + j] = topv[tid * MCAND + j];
            pi[base + j] = topi[tid * MCAND + j];
        }
    }
}

// ------------- K3: wave bitonic top-16-of-64 by filter value, fp64 rescore, scatter -------------
__global__ __launch_bounds__(256) void k_rescore(
    const float* __restrict__ t, const float* __restrict__ pv,
    const unsigned short* __restrict__ pi, float* __restrict__ out)
{
    const int wave = threadIdx.x >> 6;
    const int lane = threadIdx.x & 63;
    const int r = blockIdx.x * 4 + wave;
    const int panel = r >> 7, local = r & 127;

    // lane q holds candidate (split q>>3, slot q&7)
    const int sp = lane >> 3, slot = lane & 7;
    const size_t cbase = (((size_t)sp * NPANEL + panel) * 128 + local) * MCAND;
    const float v = pv[cbase + slot];
    const unsigned int idxc = pi[cbase + slot];
    // monotone key: v desc, idx asc. empty slots (v=-1e30, idx=0xFFFF) sort last.
    const unsigned int u = __float_as_uint(v);
    const unsigned int mkey = (u & 0x80000000u) ? ~u : (u | 0x80000000u);
    unsigned long long key = ((unsigned long long)mkey << 16) |
                             (unsigned long long)((~idxc) & 0xFFFFu);

    // 64-lane bitonic sort, descending
    #pragma unroll
    for (int k = 2; k <= 64; k <<= 1) {
        #pragma unroll
        for (int j = k >> 1; j > 0; j >>= 1) {
            const unsigned long long other = __shfl_xor(key, j, 64);
            const bool lower = (lane & j) == 0;
            const bool ascBlock = (lane & k) == 0;
            const bool takeMax = (lower == ascBlock);
            const bool mineBigger = key > other;
            key = (takeMax == mineBigger) ? key : other;
        }
    }
    const int cid = (int)((~(unsigned int)key) & 0xFFFFu);  // lanes 0..15: top-16 cand columns

    const float4 a0 = *(const float4*)&t[(size_t)r * DD + lane * 8];
    const float4 a1 = *(const float4*)&t[(size_t)r * DD + lane * 8 + 4];

    double bestv[KSEL];
    int    besti[KSEL];
    #pragma unroll
    for (int j = 0; j < KSEL; ++j) { bestv[j] = -1e300; besti[j] = 0x7fffffff; }

    for (int q = 0; q < RESCORE; ++q) {
        const int c = __shfl(cid, q, 64);
        const float4 v0 = *(const float4*)&t[(size_t)c * DD + lane * 8];
        const float4 v1 = *(const float4*)&t[(size_t)c * DD + lane * 8 + 4];
        double sdot = 0.0;
        sdot += (double)a0.x * (double)v0.x;
        sdot += (double)a0.y * (double)v0.y;
        sdot += (double)a0.z * (double)v0.z;
        sdot += (double)a0.w * (double)v0.w;
        sdot += (double)a1.x * (double)v1.x;
        sdot += (double)a1.y * (double)v1.y;
        sdot += (double)a1.z * (double)v1.z;
        sdot += (double)a1.w * (double)v1.w;
        #pragma unroll
        for (int off = 32; off > 0; off >>= 1)
            sdot += __shfl_down(sdot, off, 64);
        if (lane == 0) {
            if (sdot > bestv[KSEL-1] || (sdot == bestv[KSEL-1] && c < besti[KSEL-1])) {
                int p = KSEL - 1;
                while (p > 0 && (sdot > bestv[p-1] ||
                                 (sdot == bestv[p-1] && c < besti[p-1]))) {
                    bestv[p] = bestv[p-1]; besti[p] = besti[p-1]; --p;
                }
                bestv[p] = sdot; besti[p] = c;
            }
        }
    }

    if (lane == 0) {
        #pragma unroll
        for (int j = 0; j < KSEL; ++j)
            out[(size_t)besti[j] * NN + r] = 1.0f;
    }
}

extern "C" void kernel_launch(void* const* d_in, const int* in_sizes, int n_in,
                              void* d_out, int out_size, void* d_ws, size_t ws_size,
                              hipStream_t stream) {
    const int*   idx  = (const int*)d_in[0];
    const float* emb  = (const float*)d_in[1];
    const float* linw = (const float*)d_in[2];
    const float* linb = (const float*)d_in[3];
    float* out = (float*)d_out;

    // ws: t f32 32MB @0; tb bf16 16MB @32M; pv f32 4MB @48M; pi u16 2MB @52M
    float*          t  = (float*)d_ws;
    unsigned short* tb = (unsigned short*)((char*)d_ws + (size_t)32 * 1024 * 1024);
    float*          pv = (float*)((char*)d_ws + (size_t)48 * 1024 * 1024);
    unsigned short* pi = (unsigned short*)((char*)d_ws + (size_t)52 * 1024 * 1024);

    (void)hipMemsetAsync(d_out, 0, (size_t)NN * (size_t)NN * sizeof(float), stream);

    k_transform<<<dim3(256 * 8), dim3(256), 0, stream>>>(idx, emb, linw, linb, t, tb);
    k_sim_topk<<<dim3(NPANEL * NSPLIT), dim3(256), 0, stream>>>(tb, pv, pi);
    k_rescore<<<dim3(NN / 4), dim3(256), 0, stream>>>(t, pv, pi, out);
}